// Round 6
// baseline (722.230 us; speedup 1.0000x reference)
//
#include <hip/hip_runtime.h>
#include <math.h>

// FractalOpponent on MI355X, round 6.
// R3 structure (fp32, 512-block split-K GEMVs) + last-block tail fusion with
// two-level arrival counters. 28 kernels. No bf16 (L3 already serves re-reads).

#define H 2048

// ---- ws float offsets ----
constexpr int CTR_INTS = 8 * 144;               // 8 fusion points x (8 subs*16 + master@128)
constexpr int DL_OFF   = 1152;                  // dl0@+0, dl1@+4, dl3@+8
constexpr int GT_OFF   = 1168;                  // gates template [8192]
constexpr int NODE_OFF = GT_OFF + 8192;
constexpr int NODESZ   = 26624;
constexpr int THVo = 0, ATTNo = 2048, GATESo = 4096, EOo = 12288, SOo = 20480, CSo = 22528, HPo = 24576;
constexpr int FIN_OFF  = NODE_OFF + 5 * NODESZ; // fin[0]=N1, fin[1]=N3, fin[2]=N0
constexpr int FINSZ    = 8192;
constexpr int HNo = 0, AGGo = 2048, ANCo = 4096, GACCo = 6144;
constexpr int RH1_OFF  = FIN_OFF + 3 * FINSZ;
constexpr int RF1_OFF  = RH1_OFF + 2048;
constexpr int RC1_OFF  = RH1_OFF + 4096;

__device__ __forceinline__ float sigm(float v) { return 1.f / (1.f + expf(-v)); }

__device__ __forceinline__ int dsteps(const float* dl, int mx) {
  float l0 = dl[0], l1 = dl[1], l2 = dl[2];
  int ch = 0; float bv = l0;
  if (l1 > bv) { bv = l1; ch = 1; }
  if (l2 > bv) { bv = l2; ch = 2; }
  return ch < mx ? ch : mx;
}

// pred codes: 0 always | 1 s0>=1 | 2 s0>=1&&s1>=1 | 3 s0>=2 | 4 s0>=2&&s3>=1
__device__ __forceinline__ bool pred(const float* ws, int code) {
  if (code == 0) return true;
  const int s0 = dsteps(ws + DL_OFF, 2);
  switch (code) {
    case 1: return s0 >= 1;
    case 2: return s0 >= 1 && dsteps(ws + DL_OFF + 4, 1) >= 1;
    case 3: return s0 >= 2;
    case 4: return s0 >= 2 && dsteps(ws + DL_OFF + 8, 1) >= 1;
  }
  return true;
}

// Two-level arrival: returns true in exactly one (the last-arriving) block.
// grid must be 512; 8 sub-counters of 64 arrivals each, then master to 8.
__device__ __forceinline__ bool arrive_last(float* ws, int ctrIdx) {
  __shared__ int lastF;
  __threadfence();
  __syncthreads();
  if (threadIdx.x == 0) {
    unsigned* base = (unsigned*)ws + ctrIdx * 144;
    const unsigned prev = atomicAdd(base + (blockIdx.x & 7) * 16, 1u);
    int lf = 0;
    if (prev == 63u) {
      const unsigned m = atomicAdd(base + 128, 1u);
      lf = (m == 7u);
    }
    lastF = lf;
  }
  __syncthreads();
  if (lastF) { __threadfence(); return true; }
  return false;
}

// ---------- tail duties ----------
__device__ void tail_fsel(float* ws) {
  if (dsteps(ws + DL_OFF, 2) < 1) return;
  const bool deep = dsteps(ws + DL_OFF + 4, 1) >= 1;
  float* rh1 = ws + RH1_OFF; float* rf1 = ws + RF1_OFF; float* rc1 = ws + RC1_OFF;
  const float* fin = ws + FIN_OFF;
  const float* n1 = ws + NODE_OFF + 1 * NODESZ;
  const float* n2 = ws + NODE_OFF + 2 * NODESZ;
  for (int jj = threadIdx.x; jj < H; jj += 256) {
    if (deep) {
      const float gv = sigm(fin[GACCo + jj]);
      rh1[jj] = gv * fin[ANCo + jj] + (1.f - gv) * fin[HNo + jj];
      rf1[jj] = n2[SOo + jj]; rc1[jj] = n2[CSo + jj];
    } else {
      rh1[jj] = n1[HPo + jj]; rf1[jj] = n1[SOo + jj]; rc1[jj] = n1[CSo + jj];
    }
  }
}

__device__ void tail1(float* ws, float* out) {
  const int s0 = dsteps(ws + DL_OFF, 2);
  if (s0 < 1) return;
  const bool deep3 = dsteps(ws + DL_OFF + 8, 1) >= 1;
  const float* rh1 = ws + RH1_OFF; const float* rf1 = ws + RF1_OFF; const float* rc1 = ws + RC1_OFF;
  const float* fin3 = ws + FIN_OFF + FINSZ;
  float* fin0 = ws + FIN_OFF + 2 * FINSZ;
  const float* n3 = ws + NODE_OFF + 3 * NODESZ;
  const float* n4 = ws + NODE_OFF + 4 * NODESZ;
  const float* n0 = ws + NODE_OFF;
  for (int jj = threadIdx.x; jj < H; jj += 256) {
    float rh3 = 0.f, rf3v = 0.f, rc3v = 0.f;
    if (s0 >= 2) {
      if (deep3) {
        const float gv = sigm(fin3[GACCo + jj]);
        rh3 = gv * fin3[ANCo + jj] + (1.f - gv) * fin3[HNo + jj];
        rf3v = n4[SOo + jj]; rc3v = n4[CSo + jj];
      } else { rh3 = n3[HPo + jj]; rf3v = n3[SOo + jj]; rc3v = n3[CSo + jj]; }
    }
    const float r1 = rh1[jj];
    float ag = n0[HPo + jj] - 0.5f * r1;
    float hc, oF, oC;
    if (s0 >= 2) { ag += (1.f / 3.f) * rh3; hc = rh3; oF = rf3v; oC = rc3v; }
    else { hc = r1; oF = rf1[jj]; oC = rc1[jj]; }
    fin0[AGGo + jj] = ag; fin0[HNo + jj] = hc;
    out[jj] = oF; out[2 * H + jj] = oC;
  }
}

__device__ void tail2(float* ws, float* out) {
  const int s0 = dsteps(ws + DL_OFF, 2);
  const float* n0 = ws + NODE_OFF;
  const float* fin0 = ws + FIN_OFF + 2 * FINSZ;
  for (int jj = threadIdx.x; jj < H; jj += 256) {
    if (s0 == 0) {
      out[jj] = n0[SOo + jj]; out[H + jj] = n0[HPo + jj]; out[2 * H + jj] = n0[CSo + jj];
    } else {
      const float gv = sigm(fin0[GACCo + jj]);
      out[H + jj] = gv * fin0[ANCo + jj] + (1.f - gv) * fin0[HNo + jj];
    }
  }
}

// ---------- init ----------
__global__ void __launch_bounds__(256) k_init(
    float* ws, const float* b_lstm, const float* expert_b,
    const float* ram_b, const float* ag_b, const float* dr_b)
{
  const int gtid = blockIdx.x * 256 + threadIdx.x;
  const int gsz = gridDim.x * 256;
  for (int i = gtid; i < CTR_INTS; i += gsz) ((unsigned*)ws)[i] = 0u;
  if (gtid < 3) {
    ws[DL_OFF + gtid] = dr_b[gtid];
    ws[DL_OFF + 4 + gtid] = dr_b[gtid];
    ws[DL_OFF + 8 + gtid] = dr_b[gtid];
  }
  for (int i = gtid; i < 8192; i += gsz) ws[GT_OFF + i] = b_lstm[i];
  for (int n = 0; n < 5; ++n) {
    float* nb = ws + NODE_OFF + n * NODESZ;
    for (int i = gtid; i < 4096; i += gsz) nb[i] = 0.f;          // t_hv + attn
    for (int i = gtid; i < 8192; i += gsz) nb[EOo + i] = expert_b[i];
  }
  for (int f = 0; f < 3; ++f) {
    float* fb = ws + FIN_OFF + f * FINSZ;
    for (int i = gtid; i < 2048; i += gsz) { fb[ANCo + i] = ram_b[i]; fb[GACCo + i] = ag_b[i]; }
  }
}

// ---------- split-K GEMV (R3 shape): grid (N/256)*KS = 512, 256 thr ----------
// TAIL: 0 none | 1 fsel | 2 tail1 | 3 tail2
template <int TAIL>
__global__ void __launch_bounds__(256) k_gemv(
    const float* __restrict__ xA, const float* __restrict__ xB, int splitPt,
    const float* __restrict__ W, float* __restrict__ y, int K, int N, int KS,
    float* ws, float* out, int predCode,
    const float* copySrc, float* copyDst, int copyN, int ctrIdx)
{
  const bool ok = pred(ws, predCode);
  if (TAIL == 0 && !ok) return;
  const int tid = threadIdx.x, lane = tid & 63, tsub = tid >> 6;
  if (ok) {
    if (copySrc) {
      const int gid = blockIdx.x * 256 + tid;
      if (gid < copyN) copyDst[gid] = copySrc[gid];
    }
    const int G = N >> 8;
    const int g = blockIdx.x % G;
    const int s = blockIdx.x / G;
    const int chunk = K / KS, len = chunk >> 2;
    const int i0 = s * chunk + tsub * len;
    const int j = (g << 8) + (lane << 2);
    const float* Wp = W + (size_t)i0 * N + j;
    float ax = 0.f, ay = 0.f, az = 0.f, aw = 0.f;
    for (int t = 0; t < len; ++t) {
      const int i = i0 + t;
      const float xi = (i < splitPt) ? xA[i] : xB[i - splitPt];
      const float4 wv = *reinterpret_cast<const float4*>(Wp);
      ax = fmaf(xi, wv.x, ax); ay = fmaf(xi, wv.y, ay);
      az = fmaf(xi, wv.z, az); aw = fmaf(xi, wv.w, aw);
      Wp += N;
    }
    __shared__ float4 red[256];
    red[tid] = make_float4(ax, ay, az, aw);
    __syncthreads();
    if (tsub == 0) {
      float4 a = red[tid], b = red[tid + 64], c = red[tid + 128], d = red[tid + 192];
      atomicAdd(&y[j + 0], a.x + b.x + c.x + d.x);
      atomicAdd(&y[j + 1], a.y + b.y + c.y + d.y);
      atomicAdd(&y[j + 2], a.z + b.z + c.z + d.z);
      atomicAdd(&y[j + 3], a.w + b.w + c.w + d.w);
    }
  }
  if (TAIL != 0) {
    if (arrive_last(ws, ctrIdx)) {
      if (TAIL == 1) tail_fsel(ws);
      else if (TAIL == 2) tail1(ws, out);
      else tail2(ws, out);
    }
  }
}

// ---------- expert GEMV + fused LSTM + fused combine (last block) ----------
__global__ void __launch_bounds__(256) k_expert(
    const float* __restrict__ gates, const float* __restrict__ c_in,
    const float* __restrict__ Wex, float* ws, int predCode, int nodeIdx, int ctrIdx,
    int dlIdx, int finIdx, float damping, int phpNodeIdx,
    const float* __restrict__ router_w, const float* __restrict__ router_b,
    const float* __restrict__ dr_w, const float* __restrict__ dr_b)
{
  if (!pred(ws, predCode)) return;
  float* nb = ws + NODE_OFF + nodeIdx * NODESZ;
  float* eo = nb + EOo; float* so = nb + SOo; float* cs = nb + CSo; float* hp = nb + HPo;
  const int tid = threadIdx.x, lane = tid & 63, w = tid >> 6;
  const int g = blockIdx.x & 31, s = blockIdx.x >> 5;  // 32 col-groups x 16 K-slices
  const int i0 = s * 128;
  __shared__ float h2s[128];
  __shared__ float4 red[256];
  if (tid < 128) {
    const int i = i0 + tid;
    const float gi = gates[i], gf = gates[H + i], gg = gates[2 * H + i], go = gates[3 * H + i];
    const float c2 = sigm(gf) * c_in[i] + sigm(gi) * tanhf(gg);
    const float h2 = sigm(go) * tanhf(c2);
    h2s[tid] = h2;
    if (g == 0) { so[i] = h2; cs[i] = c2; }
  }
  __syncthreads();
  const int j = (g << 8) + (lane << 2);
  const int e = j >> 11, k = j & (H - 1);
  const float* Wp = Wex + ((size_t)e << 22) + (size_t)(i0 + w * 32) * H + k;
  float ax = 0.f, ay = 0.f, az = 0.f, aw = 0.f;
  for (int t = 0; t < 32; ++t) {
    const float xi = h2s[w * 32 + t];
    const float4 wv = *reinterpret_cast<const float4*>(Wp);
    ax = fmaf(xi, wv.x, ax); ay = fmaf(xi, wv.y, ay);
    az = fmaf(xi, wv.z, az); aw = fmaf(xi, wv.w, aw);
    Wp += H;
  }
  red[tid] = make_float4(ax, ay, az, aw);
  __syncthreads();
  if (w == 0) {
    float4 a = red[tid], b = red[tid + 64], c = red[tid + 128], d = red[tid + 192];
    atomicAdd(&eo[j + 0], a.x + b.x + c.x + d.x);
    atomicAdd(&eo[j + 1], a.y + b.y + c.y + d.y);
    atomicAdd(&eo[j + 2], a.z + b.z + c.z + d.z);
    atomicAdd(&eo[j + 3], a.w + b.w + c.w + d.w);
  }
  if (!arrive_last(ws, ctrIdx)) return;
  // ----- combine (single last block) -----
  float r0 = 0.f, r1 = 0.f, r2 = 0.f, r3 = 0.f;
  for (int i = tid; i < H; i += 256) {
    const float hh = so[i];
    const float4 rw = *reinterpret_cast<const float4*>(router_w + i * 4);
    r0 = fmaf(hh, rw.x, r0); r1 = fmaf(hh, rw.y, r1);
    r2 = fmaf(hh, rw.z, r2); r3 = fmaf(hh, rw.w, r3);
  }
  red[tid] = make_float4(r0, r1, r2, r3);
  __syncthreads();
  for (int off = 128; off > 0; off >>= 1) {
    if (tid < off) {
      const float4 b = red[tid + off];
      red[tid].x += b.x; red[tid].y += b.y; red[tid].z += b.z; red[tid].w += b.w;
    }
    __syncthreads();
  }
  const float4 L = red[0];
  __syncthreads();
  const float l0 = L.x + router_b[0], l1 = L.y + router_b[1];
  const float l2 = L.z + router_b[2], l3 = L.w + router_b[3];
  const float m = fmaxf(fmaxf(l0, l1), fmaxf(l2, l3));
  const float e0 = expf(l0 - m), e1 = expf(l1 - m), e2 = expf(l2 - m), e3 = expf(l3 - m);
  const float inv = 1.f / (e0 + e1 + e2 + e3);
  const float p0 = e0 * inv, p1 = e1 * inv, p2 = e2 * inv, p3 = e3 * inv;
  if (finIdx >= 0) {  // leaf: fuse parent's Ramanujan prep
    const float* php = ws + NODE_OFF + phpNodeIdx * NODESZ + HPo;
    float* hn = ws + FIN_OFF + finIdx * FINSZ + HNo;
    float* agg = ws + FIN_OFF + finIdx * FINSZ + AGGo;
    for (int jj = tid; jj < H; jj += 256) {
      const float v = p0 * eo[jj] + p1 * eo[H + jj] + p2 * eo[2 * H + jj] + p3 * eo[3 * H + jj];
      const float h0 = php[jj];
      const float hnv = h0 + damping * (v - h0);
      hn[jj] = hnv;
      agg[jj] = h0 - 0.5f * hnv;
    }
  } else {
    float* dl = ws + DL_OFF + dlIdx * 4;
    float d0 = 0.f, d1 = 0.f, d2 = 0.f;
    for (int jj = tid; jj < H; jj += 256) {
      const float v = p0 * eo[jj] + p1 * eo[H + jj] + p2 * eo[2 * H + jj] + p3 * eo[3 * H + jj];
      hp[jj] = v;
      d0 = fmaf(v, dr_w[jj * 3 + 0], d0);
      d1 = fmaf(v, dr_w[jj * 3 + 1], d1);
      d2 = fmaf(v, dr_w[jj * 3 + 2], d2);
    }
    red[tid] = make_float4(d0, d1, d2, 0.f);
    __syncthreads();
    for (int off = 128; off > 0; off >>= 1) {
      if (tid < off) {
        const float4 b = red[tid + off];
        red[tid].x += b.x; red[tid].y += b.y; red[tid].z += b.z;
      }
      __syncthreads();
    }
    if (tid == 0) {
      dl[0] = red[0].x + dr_b[0];
      dl[1] = red[0].y + dr_b[1];
      dl[2] = red[0].z + dr_b[2];
    }
  }
}

extern "C" void kernel_launch(void* const* d_in, const int* in_sizes, int n_in,
                              void* d_out, int out_size, void* d_ws, size_t ws_size,
                              hipStream_t stream) {
  const float* x        = (const float*)d_in[0];
  const float* h0in     = (const float*)d_in[1];
  const float* c0in     = (const float*)d_in[2];
  const float* Wv       = (const float*)d_in[5];
  const float* Wo       = (const float*)d_in[6];
  const float* Wih      = (const float*)d_in[7];
  const float* Whh      = (const float*)d_in[8];
  const float* b_lstm   = (const float*)d_in[9];
  const float* router_w = (const float*)d_in[10];
  const float* router_b = (const float*)d_in[11];
  const float* expert_w = (const float*)d_in[12];
  const float* expert_b = (const float*)d_in[13];
  const float* dr_w     = (const float*)d_in[14];
  const float* dr_b     = (const float*)d_in[15];
  const float* ram_w    = (const float*)d_in[16];
  const float* ram_b    = (const float*)d_in[17];
  const float* ag_w     = (const float*)d_in[18];
  const float* ag_b     = (const float*)d_in[19];
  float* out = (float*)d_out;
  float* ws  = (float*)d_ws;

  auto nbuf = [&](int n) { return ws + NODE_OFF + n * NODESZ; };
  float* finN1 = ws + FIN_OFF;
  float* finN3 = ws + FIN_OFF + FINSZ;
  float* finN0 = ws + FIN_OFF + 2 * FINSZ;

  auto gemv = [&](const float* xA, const float* xB, int splitPt, const float* W,
                  float* y, int K, int N, int KS, int predCode, int tail, int ctrIdx,
                  const float* cpS, float* cpD, int cpN) {
    const dim3 grid((N >> 8) * KS);
    switch (tail) {
      case 0: k_gemv<0><<<grid, 256, 0, stream>>>(xA, xB, splitPt, W, y, K, N, KS, ws, out, predCode, cpS, cpD, cpN, ctrIdx); break;
      case 1: k_gemv<1><<<grid, 256, 0, stream>>>(xA, xB, splitPt, W, y, K, N, KS, ws, out, predCode, cpS, cpD, cpN, ctrIdx); break;
      case 2: k_gemv<2><<<grid, 256, 0, stream>>>(xA, xB, splitPt, W, y, K, N, KS, ws, out, predCode, cpS, cpD, cpN, ctrIdx); break;
      default: k_gemv<3><<<grid, 256, 0, stream>>>(xA, xB, splitPt, W, y, K, N, KS, ws, out, predCode, cpS, cpD, cpN, ctrIdx); break;
    }
  };

  // node: Wv(+gates copy) -> Wo -> Whh -> expert(+LSTM+combine)
  auto node = [&](int n, const float* hv, const float* cv, int predCode, int ctrIdx,
                  int dlIdx, int finIdx, float damping, int phpNodeIdx) {
    float* nb = nbuf(n);
    gemv(hv, hv, H, Wv, nb + THVo, H, H, 64, predCode, 0, 0, ws + GT_OFF, nb + GATESo, 8192);
    gemv(nb + THVo, nb + THVo, H, Wo, nb + ATTNo, H, H, 64, predCode, 0, 0, nullptr, nullptr, 0);
    gemv(nb + ATTNo, nb + ATTNo, H, Whh, nb + GATESo, H, 4 * H, 16, predCode, 0, 0, nullptr, nullptr, 0);
    k_expert<<<512, 256, 0, stream>>>(nb + GATESo, cv, expert_w, ws, predCode, n, ctrIdx,
                                      dlIdx, finIdx, damping, phpNodeIdx,
                                      router_w, router_b, dr_w, dr_b);
  };

  // 1. init
  k_init<<<128, 256, 0, stream>>>(ws, b_lstm, expert_b, ram_b, ag_b, dr_b);
  // 2. gates template += x @ Wih
  gemv(x, x, H, Wih, ws + GT_OFF, H, 4 * H, 16, 0, 0, 0, nullptr, nullptr, 0);

  // N0
  node(0, h0in, c0in, 0, 0, 0, -1, 0.f, 0);
  // N1 (s0>=1)
  node(1, nbuf(0) + HPo, nbuf(0) + CSo, 1, 1, 1, -1, 0.f, 0);
  // N2 leaf (s0>=1 && s1>=1); combine writes finN1.hn/agg from php=hp1
  node(2, nbuf(1) + HPo, nbuf(1) + CSo, 2, 2, -1, 0, 0.25f, 1);
  // N1 finalize: ram -> ag(+fsel)
  gemv(finN1 + AGGo, nbuf(1) + HPo, H, ram_w, finN1 + ANCo, 2 * H, H, 64, 2, 0, 0, nullptr, nullptr, 0);
  gemv(finN1 + HNo, finN1 + ANCo, H, ag_w, finN1 + GACCo, 2 * H, H, 64, 2, 1, 5, nullptr, nullptr, 0);
  // N3 (s0>=2), inputs rh1/rc1
  node(3, ws + RH1_OFF, ws + RC1_OFF, 3, 3, 2, -1, 0.f, 0);
  // N4 leaf (s0>=2 && s3>=1)
  node(4, nbuf(3) + HPo, nbuf(3) + CSo, 4, 4, -1, 1, 0.25f, 3);
  // N3 finalize: ram -> ag(+tail1)
  gemv(finN3 + AGGo, nbuf(3) + HPo, H, ram_w, finN3 + ANCo, 2 * H, H, 64, 4, 0, 0, nullptr, nullptr, 0);
  gemv(finN3 + HNo, finN3 + ANCo, H, ag_w, finN3 + GACCo, 2 * H, H, 64, 4, 2, 6, nullptr, nullptr, 0);
  // N0 finalize: ram -> ag(+tail2)
  gemv(finN0 + AGGo, nbuf(0) + HPo, H, ram_w, finN0 + ANCo, 2 * H, H, 64, 1, 0, 0, nullptr, nullptr, 0);
  gemv(finN0 + HNo, finN0 + ANCo, H, ag_w, finN0 + GACCo, 2 * H, H, 64, 1, 3, 7, nullptr, nullptr, 0);
}

// Round 7
// 380.666 us; speedup vs baseline: 1.8973x; 1.8973x over previous
//
#include <hip/hip_runtime.h>
#include <math.h>

// FractalOpponent on MI355X, round 7: fence-free phase fusion.
// 9 launches. Each node = ONE kernel (Wv -> Wo -> Whh -> expert+LSTM -> combine)
// with resident-grid barriers (512 blocks @ 2/CU guaranteed co-resident).
// Cross-block data inside a kernel moves ONLY via device-scope atomics
// (atomicAdd accumulators) + agent-scope relaxed atomic loads/stores
// (sc-flagged, bypass stale L2, NO cache flushes -- R6's __threadfence was an
// L2 writeback-inv per block and cost ~80us/kernel).

#define H 2048

struct P {
  const float *x, *h0, *c0, *Wv, *Wo, *Wih, *Whh, *b_lstm, *router_w, *router_b,
              *expert_w, *expert_b, *dr_w, *dr_b, *ram_w, *ram_b, *ag_w, *ag_b;
  float* out;
  float* ws;
};

// ---- ws float offsets ----
constexpr int CTRU   = 2304;     // 9 kernels x 256 uints (barrier counters)
constexpr int DL     = 2304;     // 3 x 4 floats: depth-logit accumulators (dl0,dl1,dl3)
constexpr int GT     = 2320;     // gates-template acc (x@Wih), 8192
constexpr int NODE   = 10512;    // 5 x NODESZ
constexpr int NODESZ = 26624;
constexpr int THV = 0, ATT = 2048, GAC = 4096, EO = 12288, SO = 20480, CS = 22528, HP = 24576;
constexpr int FIN    = NODE + 5 * NODESZ;  // 3 x FINSZ: [0]=N1, [1]=N3, [2]=N0
constexpr int FINSZ  = 8192;
constexpr int ANC = 0, GCC = 2048, HNo = 4096, AGGo = 6144;
constexpr int RH1 = FIN + 3 * FINSZ;
constexpr int RF1 = RH1 + 2048;
constexpr int RC1 = RH1 + 4096;

__device__ __forceinline__ float sigm(float v) { return 1.f / (1.f + expf(-v)); }

__device__ __forceinline__ float coh_f(const float* p) {
  return __hip_atomic_load(p, __ATOMIC_RELAXED, __HIP_MEMORY_SCOPE_AGENT);
}
__device__ __forceinline__ void coh_st(float* p, float v) {
  __hip_atomic_store(p, v, __ATOMIC_RELAXED, __HIP_MEMORY_SCOPE_AGENT);
}

__device__ __forceinline__ int dsteps(const float* dla, const float* drb, int mx) {
  const float l0 = dla[0] + drb[0], l1 = dla[1] + drb[1], l2 = dla[2] + drb[2];
  int ch = 0; float bv = l0;
  if (l1 > bv) { bv = l1; ch = 1; }
  if (l2 > bv) { bv = l2; ch = 2; }
  return ch < mx ? ch : mx;
}

// pred codes: 0 always | 1 s0>=1 | 2 s0>=1&&s1>=1 | 3 s0>=2 | 4 s0>=2&&s3>=1
__device__ __forceinline__ bool pred(const float* ws, const float* drb, int code) {
  if (code == 0) return true;
  const int s0 = dsteps(ws + DL, drb, 2);
  switch (code) {
    case 1: return s0 >= 1;
    case 2: return s0 >= 1 && dsteps(ws + DL + 4, drb, 1) >= 1;
    case 3: return s0 >= 2;
    case 4: return s0 >= 2 && dsteps(ws + DL + 8, drb, 1) >= 1;
  }
  return true;
}

// Resident-grid barrier for grid=512, fence-free. Two-level monotonic counters:
// 8 sub-lines (64 arrivals each) -> master (8). Poll with s_sleep + timeout valve.
__device__ __forceinline__ void resbar(unsigned* ctr, int phase) {
  asm volatile("s_waitcnt vmcnt(0)" ::: "memory");  // per-wave: drain my atomics
  __syncthreads();
  if (threadIdx.x == 0) {
    unsigned* sub = ctr + (blockIdx.x & 7) * 16;
    unsigned* master = ctr + 128;
    const unsigned prev = __hip_atomic_fetch_add(sub, 1u, __ATOMIC_RELAXED, __HIP_MEMORY_SCOPE_AGENT);
    if (prev == (unsigned)(64 * phase) - 1u)
      __hip_atomic_fetch_add(master, 1u, __ATOMIC_RELAXED, __HIP_MEMORY_SCOPE_AGENT);
    long t = 0;
    while (__hip_atomic_load(master, __ATOMIC_RELAXED, __HIP_MEMORY_SCOPE_AGENT) <
           (unsigned)(8 * phase)) {
      __builtin_amdgcn_s_sleep(8);
      if (++t > 20000000L) break;  // safety valve: fail absmax, not hang
    }
  }
  __syncthreads();
}

// Split-K GEMV phase. y[j] += sum_i x[i]*W[i,j] over this block's slice.
// xmode: 0 = plain concat(xA,xB @ splitPt); 1 = coherent xA (same-kernel data);
//        2 = concat(xA plain, xBias + coherent xB)  [ag-gate input]
__device__ __forceinline__ void gemv_phase(
    int bid, int G, int chunk,
    const float* xA, const float* xB, int splitPt, const float* xBias, int xmode,
    const float* __restrict__ W, float* __restrict__ y, int N,
    float* shx, float4* red)
{
  const int tid = threadIdx.x, lane = tid & 63, tsub = tid >> 6;
  const int g = bid % G, s = bid / G;
  const int base = s * chunk;
  for (int idx = tid; idx < chunk; idx += 256) {
    const int i = base + idx;
    float v;
    if (xmode == 0)      v = (i < splitPt) ? xA[i] : xB[i - splitPt];
    else if (xmode == 1) v = coh_f(xA + i);
    else                 v = (i < splitPt) ? xA[i] : (xBias[i - splitPt] + coh_f(xB + (i - splitPt)));
    shx[idx] = v;
  }
  __syncthreads();
  const int len = chunk >> 2;
  const int j = (g << 8) + (lane << 2);
  const float* Wp = W + (size_t)(base + tsub * len) * N + j;
  float ax = 0.f, ay = 0.f, az = 0.f, aw = 0.f;
  for (int t = 0; t < len; ++t) {
    const float xi = shx[tsub * len + t];
    const float4 wv = *reinterpret_cast<const float4*>(Wp);
    ax = fmaf(xi, wv.x, ax); ay = fmaf(xi, wv.y, ay);
    az = fmaf(xi, wv.z, az); aw = fmaf(xi, wv.w, aw);
    Wp += N;
  }
  red[tid] = make_float4(ax, ay, az, aw);
  __syncthreads();
  if (tsub == 0) {
    float4 a = red[tid], b = red[tid + 64], c = red[tid + 128], d = red[tid + 192];
    atomicAdd(&y[j + 0], a.x + b.x + c.x + d.x);
    atomicAdd(&y[j + 1], a.y + b.y + c.y + d.y);
    atomicAdd(&y[j + 2], a.z + b.z + c.z + d.z);
    atomicAdd(&y[j + 3], a.w + b.w + c.w + d.w);
  }
}

// Expert GEMV + fused LSTM. gates = b_lstm + gt_acc + gates_acc (coherent).
__device__ void expert_phase(const P& p, float* nb, const float* c_in, const float* gt,
                             float* shx, float4* red)
{
  const int tid = threadIdx.x, lane = tid & 63, w = tid >> 6;
  const int g = blockIdx.x & 31, s = blockIdx.x >> 5;
  const int i0 = s * 128;
  if (tid < 128) {
    const int i = i0 + tid;
    const float gi = p.b_lstm[i]         + coh_f(gt + i)         + coh_f(nb + GAC + i);
    const float gf = p.b_lstm[H + i]     + coh_f(gt + H + i)     + coh_f(nb + GAC + H + i);
    const float gg = p.b_lstm[2 * H + i] + coh_f(gt + 2 * H + i) + coh_f(nb + GAC + 2 * H + i);
    const float go = p.b_lstm[3 * H + i] + coh_f(gt + 3 * H + i) + coh_f(nb + GAC + 3 * H + i);
    const float c2 = sigm(gf) * c_in[i] + sigm(gi) * tanhf(gg);
    const float h2 = sigm(go) * tanhf(c2);
    shx[tid] = h2;
    if (g == 0) { coh_st(nb + SO + i, h2); coh_st(nb + CS + i, c2); }
  }
  __syncthreads();
  const int j = (g << 8) + (lane << 2);
  const int e = j >> 11, k = j & (H - 1);
  const float* Wp = p.expert_w + ((size_t)e << 22) + (size_t)(i0 + w * 32) * H + k;
  float ax = 0.f, ay = 0.f, az = 0.f, aw = 0.f;
  for (int t = 0; t < 32; ++t) {
    const float xi = shx[w * 32 + t];
    const float4 wv = *reinterpret_cast<const float4*>(Wp);
    ax = fmaf(xi, wv.x, ax); ay = fmaf(xi, wv.y, ay);
    az = fmaf(xi, wv.z, az); aw = fmaf(xi, wv.w, aw);
    Wp += H;
  }
  red[tid] = make_float4(ax, ay, az, aw);
  __syncthreads();
  if (w == 0) {
    float4 a = red[tid], b = red[tid + 64], c = red[tid + 128], d = red[tid + 192];
    atomicAdd(&nb[EO + j + 0], a.x + b.x + c.x + d.x);
    atomicAdd(&nb[EO + j + 1], a.y + b.y + c.y + d.y);
    atomicAdd(&nb[EO + j + 2], a.z + b.z + c.z + d.z);
    atomicAdd(&nb[EO + j + 3], a.w + b.w + c.w + d.w);
  }
}

// Combine phase: blocks 0..7 (jj = bid*256+tid covers 2048).
// Router softmax (redundant per block) -> hp or leaf Ramanujan prep; dl via atomicAdd.
__device__ void combine_phase(const P& p, float* nb, float* dla, int leaf, float damping,
                              const float* php, float* hn, float* agg, float4* red)
{
  const int tid = threadIdx.x;
  float r0 = 0.f, r1 = 0.f, r2 = 0.f, r3 = 0.f;
  for (int i = tid; i < H; i += 256) {
    const float hh = coh_f(nb + SO + i);
    const float4 rw = *reinterpret_cast<const float4*>(p.router_w + i * 4);
    r0 = fmaf(hh, rw.x, r0); r1 = fmaf(hh, rw.y, r1);
    r2 = fmaf(hh, rw.z, r2); r3 = fmaf(hh, rw.w, r3);
  }
  red[tid] = make_float4(r0, r1, r2, r3);
  __syncthreads();
  for (int off = 128; off > 0; off >>= 1) {
    if (tid < off) {
      const float4 b = red[tid + off];
      red[tid].x += b.x; red[tid].y += b.y; red[tid].z += b.z; red[tid].w += b.w;
    }
    __syncthreads();
  }
  const float4 L = red[0];
  __syncthreads();
  const float l0 = L.x + p.router_b[0], l1 = L.y + p.router_b[1];
  const float l2 = L.z + p.router_b[2], l3 = L.w + p.router_b[3];
  const float m = fmaxf(fmaxf(l0, l1), fmaxf(l2, l3));
  const float e0 = expf(l0 - m), e1 = expf(l1 - m), e2 = expf(l2 - m), e3 = expf(l3 - m);
  const float inv = 1.f / (e0 + e1 + e2 + e3);
  const float q0 = e0 * inv, q1 = e1 * inv, q2 = e2 * inv, q3 = e3 * inv;
  const int jj = blockIdx.x * 256 + tid;
  const float v = q0 * (p.expert_b[jj]         + coh_f(nb + EO + jj))
                + q1 * (p.expert_b[H + jj]     + coh_f(nb + EO + H + jj))
                + q2 * (p.expert_b[2 * H + jj] + coh_f(nb + EO + 2 * H + jj))
                + q3 * (p.expert_b[3 * H + jj] + coh_f(nb + EO + 3 * H + jj));
  if (leaf) {
    const float h0v = php[jj];
    const float hnv = h0v + damping * (v - h0v);
    hn[jj] = hnv;
    agg[jj] = h0v - 0.5f * hnv;
  } else {
    nb[HP + jj] = v;
    red[tid] = make_float4(v * p.dr_w[jj * 3 + 0], v * p.dr_w[jj * 3 + 1], v * p.dr_w[jj * 3 + 2], 0.f);
    __syncthreads();
    for (int off = 128; off > 0; off >>= 1) {
      if (tid < off) {
        const float4 b = red[tid + off];
        red[tid].x += b.x; red[tid].y += b.y; red[tid].z += b.z;
      }
      __syncthreads();
    }
    if (tid == 0) {
      atomicAdd(&dla[0], red[0].x);
      atomicAdd(&dla[1], red[0].y);
      atomicAdd(&dla[2], red[0].z);
    }
  }
}

// ---- tail phases (blocks 0..7) ----
__device__ void tail_fsel(const P& p, float* ws) {
  if (dsteps(ws + DL, p.dr_b, 2) < 1) return;
  const bool deep = dsteps(ws + DL + 4, p.dr_b, 1) >= 1;
  const int jj = blockIdx.x * 256 + threadIdx.x;
  const float* n1 = ws + NODE + 1 * NODESZ;
  const float* n2 = ws + NODE + 2 * NODESZ;
  const float* fb = ws + FIN;
  float rh, rf, rc;
  if (deep) {
    const float gacc = p.ag_b[jj] + coh_f(fb + GCC + jj);
    const float anc  = p.ram_b[jj] + coh_f(fb + ANC + jj);
    const float hnv  = fb[HNo + jj];
    const float g = sigm(gacc);
    rh = g * anc + (1.f - g) * hnv;
    rf = n2[SO + jj]; rc = n2[CS + jj];
  } else {
    rh = n1[HP + jj]; rf = n1[SO + jj]; rc = n1[CS + jj];
  }
  ws[RH1 + jj] = rh; ws[RF1 + jj] = rf; ws[RC1 + jj] = rc;
}

__device__ void tail1(const P& p, float* ws) {
  const int s0 = dsteps(ws + DL, p.dr_b, 2);
  if (s0 < 1) return;
  const int jj = blockIdx.x * 256 + threadIdx.x;
  const float* n0 = ws + NODE;
  const float* n3 = ws + NODE + 3 * NODESZ;
  const float* n4 = ws + NODE + 4 * NODESZ;
  const float* fb3 = ws + FIN + FINSZ;
  float* fb0 = ws + FIN + 2 * FINSZ;
  const float r1 = ws[RH1 + jj];
  float rh3 = 0.f, rf3 = 0.f, rc3 = 0.f;
  if (s0 >= 2) {
    if (dsteps(ws + DL + 8, p.dr_b, 1) >= 1) {
      const float gacc = p.ag_b[jj] + coh_f(fb3 + GCC + jj);
      const float anc  = p.ram_b[jj] + coh_f(fb3 + ANC + jj);
      const float hnv  = fb3[HNo + jj];
      const float g = sigm(gacc);
      rh3 = g * anc + (1.f - g) * hnv;
      rf3 = n4[SO + jj]; rc3 = n4[CS + jj];
    } else { rh3 = n3[HP + jj]; rf3 = n3[SO + jj]; rc3 = n3[CS + jj]; }
  }
  float ag = n0[HP + jj] - 0.5f * r1;
  float hc, oF, oC;
  if (s0 >= 2) { ag += (1.f / 3.f) * rh3; hc = rh3; oF = rf3; oC = rc3; }
  else { hc = r1; oF = ws[RF1 + jj]; oC = ws[RC1 + jj]; }
  fb0[AGGo + jj] = ag; fb0[HNo + jj] = hc;
  p.out[jj] = oF; p.out[2 * H + jj] = oC;
}

__device__ void tail2(const P& p, float* ws) {
  const int s0 = dsteps(ws + DL, p.dr_b, 2);
  const int jj = blockIdx.x * 256 + threadIdx.x;
  const float* n0 = ws + NODE;
  const float* fb0 = ws + FIN + 2 * FINSZ;
  if (s0 == 0) {
    p.out[jj] = n0[SO + jj]; p.out[H + jj] = n0[HP + jj]; p.out[2 * H + jj] = n0[CS + jj];
  } else {
    const float gacc = p.ag_b[jj] + coh_f(fb0 + GCC + jj);
    const float anc  = p.ram_b[jj] + coh_f(fb0 + ANC + jj);
    const float hc   = fb0[HNo + jj];
    const float g = sigm(gacc);
    p.out[H + jj] = g * anc + (1.f - g) * hc;
  }
}

// ---- kernels ----
__global__ void __launch_bounds__(256, 2) k_init(P p) {
  float* ws = p.ws;
  const int gtid = blockIdx.x * 256 + threadIdx.x;
  const int gsz = 512 * 256;
  unsigned* u = (unsigned*)ws;
  for (int i = gtid; i < CTRU; i += gsz) u[i] = 0u;
  for (int i = gtid; i < 12; i += gsz) ws[DL + i] = 0.f;
  for (int i = gtid; i < 8192; i += gsz) ws[GT + i] = 0.f;
  for (int n = 0; n < 5; ++n) {
    float* nb = ws + NODE + n * NODESZ;
    for (int i = gtid; i < 20480; i += gsz) nb[i] = 0.f;   // thv, att, gates_acc, eo_acc
  }
  for (int q = 0; q < 3; ++q) {
    float* fb = ws + FIN + q * FINSZ;
    for (int i = gtid; i < 4096; i += gsz) fb[i] = 0.f;    // anc_acc, gcc_acc
  }
}

__global__ void __launch_bounds__(256, 2) k_node(
    P p, int nodeIdx, int ctrIdx, int predCode,
    const float* hv, const float* cv,
    int leaf, float damping, const float* php, float* hn, float* agg,
    float* dla, int withWih)
{
  float* ws = p.ws;
  if (!pred(ws, p.dr_b, predCode)) return;
  __shared__ float shx[256];
  __shared__ float4 red[256];
  float* nb = ws + NODE + nodeIdx * NODESZ;
  unsigned* ctr = (unsigned*)ws + ctrIdx * 256;
  // P0: t_hv = hv @ Wv  (node 0 also: gt = x @ Wih on blocks 256..511)
  if (withWih) {
    if (blockIdx.x < 256)
      gemv_phase(blockIdx.x, 8, 64, hv, hv, 1 << 30, nullptr, 0, p.Wv, nb + THV, H, shx, red);
    else
      gemv_phase(blockIdx.x - 256, 32, 256, p.x, p.x, 1 << 30, nullptr, 0, p.Wih, ws + GT, 4 * H, shx, red);
  } else {
    gemv_phase(blockIdx.x, 8, 32, hv, hv, 1 << 30, nullptr, 0, p.Wv, nb + THV, H, shx, red);
  }
  resbar(ctr, 1);
  // P1: attn = t_hv @ Wo
  gemv_phase(blockIdx.x, 8, 32, nb + THV, nullptr, 0, nullptr, 1, p.Wo, nb + ATT, H, shx, red);
  resbar(ctr, 2);
  // P2: gates_acc = attn @ Whh
  gemv_phase(blockIdx.x, 32, 128, nb + ATT, nullptr, 0, nullptr, 1, p.Whh, nb + GAC, 4 * H, shx, red);
  resbar(ctr, 3);
  // P3: LSTM + expert GEMV
  expert_phase(p, nb, cv, ws + GT, shx, red);
  resbar(ctr, 4);
  // P4: combine (blocks 0..7)
  if (blockIdx.x >= 8) return;
  combine_phase(p, nb, dla, leaf, damping, php, hn, agg, red);
}

__global__ void __launch_bounds__(256, 2) k_fin(
    P p, int finIdx, int ctrIdx, int predCode,
    const float* aggv, const float* phpv, const float* hnv, int tailKind)
{
  float* ws = p.ws;
  __shared__ float shx[256];
  __shared__ float4 red[256];
  float* fb = ws + FIN + finIdx * FINSZ;
  unsigned* ctr = (unsigned*)ws + ctrIdx * 256;
  const bool ok = pred(ws, p.dr_b, predCode);
  if (ok) {
    // P0: anchor_acc = concat(agg, php) @ ram_w
    gemv_phase(blockIdx.x, 8, 64, aggv, phpv, H, nullptr, 0, p.ram_w, fb + ANC, H, shx, red);
    resbar(ctr, 1);
    // P1: gacc_acc = concat(hn, ram_b + anchor_acc) @ ag_w
    gemv_phase(blockIdx.x, 8, 64, hnv, fb + ANC, H, p.ram_b, 2, p.ag_w, fb + GCC, H, shx, red);
    resbar(ctr, 2);
  }
  if (blockIdx.x >= 8) return;
  if (tailKind == 1) tail_fsel(p, ws);
  else if (tailKind == 2) tail1(p, ws);
  else tail2(p, ws);
}

extern "C" void kernel_launch(void* const* d_in, const int* in_sizes, int n_in,
                              void* d_out, int out_size, void* d_ws, size_t ws_size,
                              hipStream_t stream) {
  P p;
  p.x = (const float*)d_in[0];  p.h0 = (const float*)d_in[1];  p.c0 = (const float*)d_in[2];
  p.Wv = (const float*)d_in[5]; p.Wo = (const float*)d_in[6];
  p.Wih = (const float*)d_in[7]; p.Whh = (const float*)d_in[8];
  p.b_lstm = (const float*)d_in[9];
  p.router_w = (const float*)d_in[10]; p.router_b = (const float*)d_in[11];
  p.expert_w = (const float*)d_in[12]; p.expert_b = (const float*)d_in[13];
  p.dr_w = (const float*)d_in[14]; p.dr_b = (const float*)d_in[15];
  p.ram_w = (const float*)d_in[16]; p.ram_b = (const float*)d_in[17];
  p.ag_w = (const float*)d_in[18]; p.ag_b = (const float*)d_in[19];
  p.out = (float*)d_out;
  p.ws = (float*)d_ws;

  float* ws = p.ws;
  auto nb = [&](int n) { return ws + NODE + n * NODESZ; };
  float* fb1 = ws + FIN;
  float* fb3 = ws + FIN + FINSZ;
  float* fb0 = ws + FIN + 2 * FINSZ;

  k_init<<<512, 256, 0, stream>>>(p);
  // N0 (depth 0) + Wih template
  k_node<<<512, 256, 0, stream>>>(p, 0, 0, 0, p.h0, p.c0,
                                  0, 0.f, nullptr, nullptr, nullptr, ws + DL, 1);
  // N1 (depth 1), pred s0>=1
  k_node<<<512, 256, 0, stream>>>(p, 1, 1, 1, nb(0) + HP, nb(0) + CS,
                                  0, 0.f, nullptr, nullptr, nullptr, ws + DL + 4, 0);
  // N2 (depth 2 leaf), pred s0>=1 && s1>=1; combine preps N1 finalize
  k_node<<<512, 256, 0, stream>>>(p, 2, 2, 2, nb(1) + HP, nb(1) + CS,
                                  1, 0.25f, nb(1) + HP, fb1 + HNo, fb1 + AGGo, nullptr, 0);
  // N1 finalize + fsel
  k_fin<<<512, 256, 0, stream>>>(p, 0, 3, 2, fb1 + AGGo, nb(1) + HP, fb1 + HNo, 1);
  // N3 (depth 1), pred s0>=2, inputs rh1/rc1
  k_node<<<512, 256, 0, stream>>>(p, 3, 4, 3, ws + RH1, ws + RC1,
                                  0, 0.f, nullptr, nullptr, nullptr, ws + DL + 8, 0);
  // N4 (depth 2 leaf), pred s0>=2 && s3>=1; combine preps N3 finalize
  k_node<<<512, 256, 0, stream>>>(p, 4, 5, 4, nb(3) + HP, nb(3) + CS,
                                  1, 0.25f, nb(3) + HP, fb3 + HNo, fb3 + AGGo, nullptr, 0);
  // N3 finalize + tail1 (N3 select, N0 prep, out F/C)
  k_fin<<<512, 256, 0, stream>>>(p, 1, 6, 4, fb3 + AGGo, nb(3) + HP, fb3 + HNo, 2);
  // N0 finalize + tail2 (final h / leaf passthrough)
  k_fin<<<512, 256, 0, stream>>>(p, 2, 7, 1, fb0 + AGGo, nb(0) + HP, fb0 + HNo, 3);
}